// Round 1
// baseline (433.699 us; speedup 1.0000x reference)
//
#include <hip/hip_runtime.h>
#include <hip/hip_bf16.h>

#define B_SZ 32
#define T_TOK 1024
#define H_DIM 256
#define T_MEL 4096
#define K_SZ 5
#define TB 16   // t-values per conv block

// ---------------- repack W: [H_out][H_in][K] -> [K][H_in][H_out] ----------------
__global__ __launch_bounds__(256) void repack_w(const float* __restrict__ w,
                                                float* __restrict__ wr) {
    int idx = blockIdx.x * 256 + threadIdx.x;          // (k*256+hi)*256+ho
    int ho = idx & 255;
    int hi = (idx >> 8) & 255;
    int k  = idx >> 16;
    wr[idx] = w[(ho * H_DIM + hi) * K_SZ + k];
}

// ---------------- sequential clipped cumsum (bit-matches np.cumsum) -------------
__global__ void scan_kernel(const float* __restrict__ a, const int* __restrict__ gt,
                            float* __restrict__ cum) {
    int b = blockIdx.x;
    if (threadIdx.x != 0) return;
    float c = 0.f;
    float lim = (float)gt[b];
    const float* ab = a + b * T_TOK;
    float* cb = cum + b * T_TOK;
    for (int t = 0; t < T_TOK; ++t) {
        c += ab[t];
        cb[t] = fminf(c, lim);
    }
}

// ---------------- conv1d(SAME,K=5) + LayerNorm + ReLU + dot -> m[b,t] -----------
__global__ __launch_bounds__(256) void conv_fused(const float* __restrict__ x,
                                                  const float* __restrict__ wr,
                                                  const float* __restrict__ cb,
                                                  const float* __restrict__ g,
                                                  const float* __restrict__ beta,
                                                  const float* __restrict__ lw,
                                                  const float* __restrict__ lb,
                                                  const int* __restrict__ tn,
                                                  float* __restrict__ m_out) {
    __shared__ float xs[(TB + 4) * H_DIM];   // 20 rows x 256 = 20KB; reused for m_tile
    __shared__ float red[8];
    int b = blockIdx.x >> 6;           // 64 tiles per batch row
    int t0 = (blockIdx.x & 63) * TB;
    int h = threadIdx.x;
    int lane = h & 63, wid = h >> 6;

    // stage x rows t0-2 .. t0+17 (zero-pad outside [0,T_TOK))
    for (int r = 0; r < TB + 4; ++r) {
        int t = t0 - 2 + r;
        float v = 0.f;
        if (t >= 0 && t < T_TOK) v = x[((size_t)b * T_TOK + t) * H_DIM + h];
        xs[r * H_DIM + h] = v;
    }
    __syncthreads();

    float acc[TB];
#pragma unroll
    for (int i = 0; i < TB; ++i) acc[i] = 0.f;

    for (int hi = 0; hi < H_DIM; ++hi) {
        float xv[TB + 4];
#pragma unroll
        for (int r = 0; r < TB + 4; ++r) xv[r] = xs[r * H_DIM + hi];  // broadcast reads
#pragma unroll
        for (int k = 0; k < K_SZ; ++k) {
            float w = wr[(k * H_DIM + hi) * H_DIM + h];               // coalesced, L2-hot
#pragma unroll
            for (int tt = 0; tt < TB; ++tt) acc[tt] += xv[tt + k] * w;
        }
    }
    float bias = cb[h];
    __syncthreads();                       // xs reads done; reuse as m_tile
#pragma unroll
    for (int tt = 0; tt < TB; ++tt) xs[tt * H_DIM + h] = acc[tt] + bias;
    __syncthreads();

    float gh = g[h], bh = beta[h], lwh = lw[h];
    int ntok = tn[b];
    for (int tt = 0; tt < TB; ++tt) {
        float v = xs[tt * H_DIM + h];
        float s = v;
#pragma unroll
        for (int off = 32; off; off >>= 1) s += __shfl_down(s, off);
        if (lane == 0) red[wid] = s;
        __syncthreads();
        float mu = (red[0] + red[1] + red[2] + red[3]) * (1.f / H_DIM);
        float d = v - mu;
        float s2 = d * d;
#pragma unroll
        for (int off = 32; off; off >>= 1) s2 += __shfl_down(s2, off);
        if (lane == 0) red[4 + wid] = s2;
        __syncthreads();
        float var = (red[4] + red[5] + red[6] + red[7]) * (1.f / H_DIM);
        float y = d * rsqrtf(var + 1e-5f) * gh + bh;
        y = fmaxf(y, 0.f);
        float r = y * lwh;
#pragma unroll
        for (int off = 32; off; off >>= 1) r += __shfl_down(r, off);
        __syncthreads();                  // red[0..3] consumed by everyone above
        if (lane == 0) red[wid] = r;
        __syncthreads();
        if (h == 0) {
            float mv = red[0] + red[1] + red[2] + red[3] + lb[0];
            int t = t0 + tt;
            if (t >= ntok) mv = 0.f;
            m_out[b * T_TOK + t] = mv;
        }
        __syncthreads();
    }
}

// ---------------- mels_num_predicted = int(sum(exp(m[valid]))) as float ---------
__global__ __launch_bounds__(256) void mels_kernel(const float* __restrict__ m,
                                                   const int* __restrict__ tn,
                                                   float* __restrict__ out) {
    int b = blockIdx.x;
    int tid = threadIdx.x;
    int n = tn[b];
    float s = 0.f;
    for (int t = tid; t < T_TOK; t += 256)
        if (t < n) s += expf(m[b * T_TOK + t]);
    __shared__ float red[4];
    int lane = tid & 63, wid = tid >> 6;
#pragma unroll
    for (int off = 32; off; off >>= 1) s += __shfl_down(s, off);
    if (lane == 0) red[wid] = s;
    __syncthreads();
    if (tid == 0) {
        float tot = red[0] + red[1] + red[2] + red[3];
        out[b] = (float)((int)tot);
    }
}

// ---------------- expansion: searchsorted + row gather --------------------------
__global__ __launch_bounds__(256) void expand_kernel(const float* __restrict__ x,
                                                     const float* __restrict__ cum,
                                                     float* __restrict__ out) {
    int wid = threadIdx.x >> 6;
    int lane = threadIdx.x & 63;
    int fidx = blockIdx.x * 4 + wid;      // frame id over B*T_MEL
    int b = fidx >> 12;                   // T_MEL = 4096
    float ff = (float)(fidx & 4095);
    const float* cb = cum + b * T_TOK;
    int lo = 0, hi = T_TOK;
    while (lo < hi) {                      // searchsorted side='right'
        int mid = (lo + hi) >> 1;
        if (cb[mid] <= ff) lo = mid + 1; else hi = mid;
    }
    float4 v = make_float4(0.f, 0.f, 0.f, 0.f);
    if (lo < T_TOK) {
        const float4* src = (const float4*)(x + ((size_t)b * T_TOK + lo) * H_DIM);
        v = src[lane];
    }
    ((float4*)(out + (size_t)fidx * H_DIM))[lane] = v;
}

extern "C" void kernel_launch(void* const* d_in, const int* in_sizes, int n_in,
                              void* d_out, int out_size, void* d_ws, size_t ws_size,
                              hipStream_t stream) {
    const float* x          = (const float*)d_in[0];
    const int*   token_nums = (const int*)d_in[1];
    const float* align      = (const float*)d_in[2];
    const int*   gt         = (const int*)d_in[3];
    // conv1 branch (d_in[4..7]) is dead in the reference
    const float* w2  = (const float*)d_in[8];
    const float* b2  = (const float*)d_in[9];
    const float* g2  = (const float*)d_in[10];
    const float* be2 = (const float*)d_in[11];
    const float* lw  = (const float*)d_in[12];
    const float* lb  = (const float*)d_in[13];

    float* out   = (float*)d_out;
    float* xnew  = out;                                        // [B, T_MEL, H]
    float* m_out = out + (size_t)B_SZ * T_MEL * H_DIM;         // [B, T_TOK]
    float* mels  = m_out + (size_t)B_SZ * T_TOK;               // [B]

    float* wr  = (float*)d_ws;                                 // 5*256*256 f32
    float* cum = wr + K_SZ * H_DIM * H_DIM;                    // 32*1024 f32

    repack_w<<<(K_SZ * H_DIM * H_DIM) / 256, 256, 0, stream>>>(w2, wr);
    scan_kernel<<<B_SZ, 64, 0, stream>>>(align, gt, cum);
    conv_fused<<<B_SZ * (T_TOK / TB), 256, 0, stream>>>(x, wr, b2, g2, be2, lw, lb,
                                                        token_nums, m_out);
    mels_kernel<<<B_SZ, 256, 0, stream>>>(m_out, token_nums, mels);
    expand_kernel<<<(B_SZ * T_MEL) / 4, 256, 0, stream>>>(x, cum, xnew);
}

// Round 2
// 127.430 us; speedup vs baseline: 3.4034x; 3.4034x over previous
//
#include <hip/hip_runtime.h>
#include <hip/hip_bf16.h>

#define B_SZ 32
#define T_TOK 1024
#define H_DIM 256
#define T_MEL 4096
#define K_SZ 5
#define BM 64
#define ROWS (BM + 4)   // 68 staged x rows

typedef __attribute__((ext_vector_type(8))) short bf16x8;
typedef __attribute__((ext_vector_type(4))) float f32x4;

__device__ inline short f2bf(float f) {
    __hip_bfloat16 h = __float2bfloat16(f);
    return *reinterpret_cast<short*>(&h);
}

// ---- repack W [H_out][H_in][K] f32 -> bf16 fragment order [s][n][lane][j] ----
// K-order: kk = k*256 + hi; step s covers kk in [s*32, s*32+32)
// B-fragment (16x16x32): col(ho) = lane&15, kk_local = 8*(lane>>4)+j
__global__ __launch_bounds__(256) void repack_w(const float* __restrict__ w,
                                                short* __restrict__ wr) {
    int idx = blockIdx.x * 256 + threadIdx.x;   // 40*16*64 threads
    int lane = idx & 63;
    int n = (idx >> 6) & 15;
    int s = idx >> 10;
    int k = s >> 3;
    int hi0 = (s & 7) * 32 + (lane >> 4) * 8;
    int ho = n * 16 + (lane & 15);
    short out[8];
#pragma unroll
    for (int j = 0; j < 8; ++j)
        out[j] = f2bf(w[(ho * H_DIM + hi0 + j) * K_SZ + k]);
    *reinterpret_cast<bf16x8*>(wr + (size_t)idx * 8) = *reinterpret_cast<bf16x8*>(out);
}

// ---- sequential clipped cumsum (bit-matches np.cumsum; keeps gather exact) ----
__global__ void scan_kernel(const float* __restrict__ a, const int* __restrict__ gt,
                            float* __restrict__ cum) {
    int b = blockIdx.x;
    if (threadIdx.x != 0) return;
    float c = 0.f;
    float lim = (float)gt[b];
    const float* ab = a + b * T_TOK;
    float* cb = cum + b * T_TOK;
    for (int t = 0; t < T_TOK; ++t) {
        c += ab[t];
        cb[t] = fminf(c, lim);
    }
}

// ---- conv1d(SAME,K=5) via bf16 MFMA + fused LayerNorm+ReLU+dot -> m[b,t] ----
__global__ __launch_bounds__(512, 4) void conv_mfma(
    const float* __restrict__ x, const short* __restrict__ wr,
    const float* __restrict__ cb, const float* __restrict__ g,
    const float* __restrict__ beta, const float* __restrict__ lw,
    const float* __restrict__ lb, const int* __restrict__ tn,
    float* __restrict__ m_out)
{
    __shared__ char smem[65536];   // union: x-tile bf16 68*512B=34KB, then m-tile f32 64KB
    int b = blockIdx.x >> 4;            // 16 tiles per batch row
    int t0 = (blockIdx.x & 15) * BM;
    int tid = threadIdx.x;
    int lane = tid & 63;
    int wid = tid >> 6;
    int wm = wid >> 2, wn = wid & 3;    // 2 M-waves x 4 N-waves

    // stage x rows [t0-2, t0+66) as bf16, XOR-swizzled (G4: 512B rows)
    for (int i = tid; i < ROWS * 64; i += 512) {
        int row = i >> 6;
        int c4 = i & 63;
        int t = t0 - 2 + row;
        float4 v = make_float4(0.f, 0.f, 0.f, 0.f);
        if (t >= 0 && t < T_TOK)
            v = *reinterpret_cast<const float4*>(x + ((size_t)b * T_TOK + t) * H_DIM + c4 * 4);
        short4 h;
        h.x = f2bf(v.x); h.y = f2bf(v.y); h.z = f2bf(v.z); h.w = f2bf(v.w);
        int byte = row * 512 + c4 * 8;
        byte ^= (row & 7) << 4;
        *reinterpret_cast<short4*>(smem + byte) = h;
    }
    __syncthreads();

    const bf16x8* wf = reinterpret_cast<const bf16x8*>(wr);
    f32x4 zero = {0.f, 0.f, 0.f, 0.f};
    f32x4 acc[2][4];
#pragma unroll
    for (int mi = 0; mi < 2; ++mi)
#pragma unroll
        for (int ni = 0; ni < 4; ++ni) acc[mi][ni] = zero;

    int tb = wm * 32 + (lane & 15);     // A-fragment row base (t_loc)
    int ccol = (lane >> 4) * 16;        // byte offset of lane's 8-bf16 k-group
    int wnl = wn * 4;

    bf16x8 bc[4], bn[4];
#pragma unroll
    for (int ni = 0; ni < 4; ++ni) bc[ni] = wf[(size_t)(wnl + ni) * 64 + lane];

#pragma unroll 2
    for (int s = 0; s < 40; ++s) {
        int rbase = tb + (s >> 3);      // staged row = t_loc + k
        int cbase = (s & 7) * 64 + ccol;
        int by0 = (rbase * 512 + cbase) ^ ((rbase & 7) << 4);
        bf16x8 a0 = *reinterpret_cast<const bf16x8*>(smem + by0);
        int r1 = rbase + 16;
        int by1 = (r1 * 512 + cbase) ^ ((r1 & 7) << 4);
        bf16x8 a1 = *reinterpret_cast<const bf16x8*>(smem + by1);
        if (s < 39) {
#pragma unroll
            for (int ni = 0; ni < 4; ++ni)
                bn[ni] = wf[(size_t)((s + 1) * 16 + wnl + ni) * 64 + lane];
        }
#pragma unroll
        for (int ni = 0; ni < 4; ++ni) {
            acc[0][ni] = __builtin_amdgcn_mfma_f32_16x16x32_bf16(a0, bc[ni], acc[0][ni], 0, 0, 0);
            acc[1][ni] = __builtin_amdgcn_mfma_f32_16x16x32_bf16(a1, bc[ni], acc[1][ni], 0, 0, 0);
        }
#pragma unroll
        for (int ni = 0; ni < 4; ++ni) bc[ni] = bn[ni];
    }

    __syncthreads();                    // all x-tile reads done before LDS reuse
    float* mt = reinterpret_cast<float*>(smem);
    float cbv[4];
#pragma unroll
    for (int ni = 0; ni < 4; ++ni) cbv[ni] = cb[wn * 64 + ni * 16 + (lane & 15)];
    int trow = wm * 32 + (lane >> 4) * 4;   // D: row = 4*(lane>>4)+reg
    int hocol = wn * 64 + (lane & 15);      // D: col = lane&15
#pragma unroll
    for (int mi = 0; mi < 2; ++mi)
#pragma unroll
        for (int ni = 0; ni < 4; ++ni)
#pragma unroll
            for (int r = 0; r < 4; ++r)
                mt[(trow + mi * 16 + r) * 256 + hocol + ni * 16] = acc[mi][ni][r] + cbv[ni];
    __syncthreads();

    // LN + ReLU + dot(lw) per row; wave w owns rows [w*8, w*8+8)
    float4 g4 = *reinterpret_cast<const float4*>(g + lane * 4);
    float4 b4 = *reinterpret_cast<const float4*>(beta + lane * 4);
    float4 l4 = *reinterpret_cast<const float4*>(lw + lane * 4);
    float lb0 = lb[0];
    int ntok = tn[b];
    for (int rr = 0; rr < 8; ++rr) {
        int row = wid * 8 + rr;
        float4 v = *reinterpret_cast<const float4*>(mt + row * 256 + lane * 4);
        float s1 = v.x + v.y + v.z + v.w;
#pragma unroll
        for (int m = 32; m; m >>= 1) s1 += __shfl_xor(s1, m);
        float mu = s1 * (1.f / 256.f);
        float dx = v.x - mu, dy = v.y - mu, dz = v.z - mu, dw = v.w - mu;
        float s2 = dx * dx + dy * dy + dz * dz + dw * dw;
#pragma unroll
        for (int m = 32; m; m >>= 1) s2 += __shfl_xor(s2, m);
        float rs = rsqrtf(s2 * (1.f / 256.f) + 1e-5f);
        float yx = fmaxf(dx * rs * g4.x + b4.x, 0.f);
        float yy = fmaxf(dy * rs * g4.y + b4.y, 0.f);
        float yz = fmaxf(dz * rs * g4.z + b4.z, 0.f);
        float yw = fmaxf(dw * rs * g4.w + b4.w, 0.f);
        float dot = yx * l4.x + yy * l4.y + yz * l4.z + yw * l4.w;
#pragma unroll
        for (int m = 32; m; m >>= 1) dot += __shfl_xor(dot, m);
        if (lane == 0) {
            int t = t0 + row;
            m_out[b * T_TOK + t] = (t < ntok) ? (dot + lb0) : 0.f;
        }
    }
}

// ---- mels_num_predicted = float(int(sum(exp(m[valid])))) ----
__global__ __launch_bounds__(256) void mels_kernel(const float* __restrict__ m,
                                                   const int* __restrict__ tn,
                                                   float* __restrict__ out) {
    int b = blockIdx.x;
    int tid = threadIdx.x;
    int n = tn[b];
    float s = 0.f;
    for (int t = tid; t < T_TOK; t += 256)
        if (t < n) s += expf(m[b * T_TOK + t]);
    __shared__ float red[4];
    int lane = tid & 63, wid = tid >> 6;
#pragma unroll
    for (int off = 32; off; off >>= 1) s += __shfl_down(s, off);
    if (lane == 0) red[wid] = s;
    __syncthreads();
    if (tid == 0) {
        float tot = red[0] + red[1] + red[2] + red[3];
        out[b] = (float)((int)tot);
    }
}

// ---- expansion: searchsorted(side='right') + row gather ----
__global__ __launch_bounds__(256) void expand_kernel(const float* __restrict__ x,
                                                     const float* __restrict__ cum,
                                                     float* __restrict__ out) {
    int wid = threadIdx.x >> 6;
    int lane = threadIdx.x & 63;
    int fidx = blockIdx.x * 4 + wid;      // frame id over B*T_MEL
    int b = fidx >> 12;                   // T_MEL = 4096
    float ff = (float)(fidx & 4095);
    const float* cb = cum + b * T_TOK;
    int lo = 0, hi = T_TOK;
    while (lo < hi) {
        int mid = (lo + hi) >> 1;
        if (cb[mid] <= ff) lo = mid + 1; else hi = mid;
    }
    float4 v = make_float4(0.f, 0.f, 0.f, 0.f);
    if (lo < T_TOK) {
        const float4* src = (const float4*)(x + ((size_t)b * T_TOK + lo) * H_DIM);
        v = src[lane];
    }
    ((float4*)(out + (size_t)fidx * H_DIM))[lane] = v;
}

extern "C" void kernel_launch(void* const* d_in, const int* in_sizes, int n_in,
                              void* d_out, int out_size, void* d_ws, size_t ws_size,
                              hipStream_t stream) {
    const float* x          = (const float*)d_in[0];
    const int*   token_nums = (const int*)d_in[1];
    const float* align      = (const float*)d_in[2];
    const int*   gt         = (const int*)d_in[3];
    // conv1 branch (d_in[4..7]) is dead in the reference
    const float* w2  = (const float*)d_in[8];
    const float* b2  = (const float*)d_in[9];
    const float* g2  = (const float*)d_in[10];
    const float* be2 = (const float*)d_in[11];
    const float* lw  = (const float*)d_in[12];
    const float* lb  = (const float*)d_in[13];

    float* out   = (float*)d_out;
    float* xnew  = out;                                        // [B, T_MEL, H]
    float* m_out = out + (size_t)B_SZ * T_MEL * H_DIM;         // [B, T_TOK]
    float* mels  = m_out + (size_t)B_SZ * T_TOK;               // [B]

    short* wr  = (short*)d_ws;                                 // 40*16*64*8 bf16 = 640KB
    float* cum = (float*)((char*)d_ws + (size_t)40 * 16 * 64 * 8 * 2);

    repack_w<<<160, 256, 0, stream>>>(w2, wr);
    scan_kernel<<<B_SZ, 64, 0, stream>>>(align, gt, cum);
    conv_mfma<<<B_SZ * (T_TOK / BM), 512, 0, stream>>>(x, wr, b2, g2, be2, lw, lb,
                                                       token_nums, m_out);
    mels_kernel<<<B_SZ, 256, 0, stream>>>(m_out, token_nums, mels);
    expand_kernel<<<(B_SZ * T_MEL) / 4, 256, 0, stream>>>(x, cum, xnew);
}

// Round 3
// 86.184 us; speedup vs baseline: 5.0323x; 1.4786x over previous
//
#include <hip/hip_runtime.h>
#include <hip/hip_bf16.h>

#define B_SZ 32
#define T_TOK 1024
#define H_DIM 256
#define T_MEL 4096
#define K_SZ 5
#define BM 64
#define ROWS (BM + 4)          // 68 staged x rows
#define XS_BYTES (ROWS * 512)  // 34816
#define CONV_BLOCKS 512
#define EXPAND_BLOCKS 4096     // 8 frames per block (1/wave)

typedef __attribute__((ext_vector_type(8))) short bf16x8;
typedef __attribute__((ext_vector_type(4))) float f32x4;

__device__ inline short f2bf(float f) {
    __hip_bfloat16 h = __float2bfloat16(f);
    return *reinterpret_cast<short*>(&h);
}

// ---- prep: repack W (blocks 0..159) + sequential clipped cumsum (blocks 160..191) ----
// W repack: [H_out][H_in][K] f32 -> bf16 B-fragment order [s][n][lane][j]
//   kk = k*256 + hi; step s covers kk in [s*32, s*32+32)
//   B-fragment (16x16x32): col(ho) = lane&15, kk_local = 8*(lane>>4)+j
__global__ __launch_bounds__(256) void prep_kernel(const float* __restrict__ w,
                                                   short* __restrict__ wr,
                                                   const float* __restrict__ a,
                                                   const int* __restrict__ gt,
                                                   float* __restrict__ cum) {
    if (blockIdx.x < 160) {
        int idx = blockIdx.x * 256 + threadIdx.x;   // 40*16*64 threads
        int lane = idx & 63;
        int n = (idx >> 6) & 15;
        int s = idx >> 10;
        int k = s >> 3;
        int hi0 = (s & 7) * 32 + (lane >> 4) * 8;
        int ho = n * 16 + (lane & 15);
        short out[8];
#pragma unroll
        for (int j = 0; j < 8; ++j)
            out[j] = f2bf(w[(ho * H_DIM + hi0 + j) * K_SZ + k]);
        *reinterpret_cast<bf16x8*>(wr + (size_t)idx * 8) = *reinterpret_cast<bf16x8*>(out);
    } else {
        if (threadIdx.x != 0) return;
        int b = blockIdx.x - 160;                   // bit-matches np.cumsum order
        float c = 0.f;
        float lim = (float)gt[b];
        const float* ab = a + b * T_TOK;
        float* cb = cum + b * T_TOK;
        for (int t = 0; t < T_TOK; ++t) {
            c += ab[t];
            cb[t] = fminf(c, lim);
        }
    }
}

// ---- fused: conv1d(K=5)+LN+ReLU+dot (blocks < 512) || expansion gather (rest) ----
__global__ __launch_bounds__(512) void fused_kernel(
    const float* __restrict__ x, const short* __restrict__ wr,
    const float* __restrict__ cb, const float* __restrict__ g,
    const float* __restrict__ beta, const float* __restrict__ lw,
    const float* __restrict__ lb, const int* __restrict__ tn,
    const float* __restrict__ cum,
    float* __restrict__ m_out, float* __restrict__ xnew)
{
    __shared__ char smem[XS_BYTES + 3584];
    int tid = threadIdx.x;
    int lane = tid & 63;
    int wid = tid >> 6;

    if (blockIdx.x >= CONV_BLOCKS) {
        // ---------------- expansion: searchsorted(right) + row gather ----------------
        int fidx = (blockIdx.x - CONV_BLOCKS) * 8 + wid;   // frame over B*T_MEL
        int b = fidx >> 12;
        float ff = (float)(fidx & 4095);
        const float* cbm = cum + b * T_TOK;
        int lo = 0, hi = T_TOK;
        while (lo < hi) {
            int mid = (lo + hi) >> 1;
            if (cbm[mid] <= ff) lo = mid + 1; else hi = mid;
        }
        float4 v = make_float4(0.f, 0.f, 0.f, 0.f);
        if (lo < T_TOK)
            v = ((const float4*)(x + ((size_t)b * T_TOK + lo) * H_DIM))[lane];
        ((float4*)(xnew + (size_t)fidx * H_DIM))[lane] = v;
        return;
    }

    // ---------------- conv tile: 64 t-rows x 256 h_out via bf16 MFMA ----------------
    int b = blockIdx.x >> 4;
    int t0 = (blockIdx.x & 15) * BM;
    int wm = wid >> 2, wn = wid & 3;    // 2 M-waves x 4 N-waves

    // stage x rows [t0-2, t0+66) as bf16, XOR-swizzled (512B rows -> G4 swizzle)
    for (int i = tid; i < ROWS * 64; i += 512) {
        int row = i >> 6;
        int c4 = i & 63;
        int t = t0 - 2 + row;
        float4 v = make_float4(0.f, 0.f, 0.f, 0.f);
        if (t >= 0 && t < T_TOK)
            v = *reinterpret_cast<const float4*>(x + ((size_t)b * T_TOK + t) * H_DIM + c4 * 4);
        short4 h;
        h.x = f2bf(v.x); h.y = f2bf(v.y); h.z = f2bf(v.z); h.w = f2bf(v.w);
        int byte = row * 512 + c4 * 8;
        byte ^= (row & 7) << 4;
        *reinterpret_cast<short4*>(smem + byte) = h;
    }
    __syncthreads();

    const bf16x8* wf = reinterpret_cast<const bf16x8*>(wr);
    f32x4 zero = {0.f, 0.f, 0.f, 0.f};
    f32x4 acc[2][4];
#pragma unroll
    for (int mi = 0; mi < 2; ++mi)
#pragma unroll
        for (int ni = 0; ni < 4; ++ni) acc[mi][ni] = zero;

    int tb = wm * 32 + (lane & 15);     // A-fragment row base (t_loc)
    int ccol = (lane >> 4) * 16;        // byte offset of lane's 8-bf16 k-group
    int wnl = wn * 4;

    bf16x8 bc[4], bn[4];
#pragma unroll
    for (int ni = 0; ni < 4; ++ni) bc[ni] = wf[(size_t)(wnl + ni) * 64 + lane];

#pragma unroll 2
    for (int s = 0; s < 40; ++s) {
        int rbase = tb + (s >> 3);      // staged row = t_loc + k
        int cbase = (s & 7) * 64 + ccol;
        int by0 = (rbase * 512 + cbase) ^ ((rbase & 7) << 4);
        bf16x8 a0 = *reinterpret_cast<const bf16x8*>(smem + by0);
        int r1 = rbase + 16;
        int by1 = (r1 * 512 + cbase) ^ ((r1 & 7) << 4);
        bf16x8 a1 = *reinterpret_cast<const bf16x8*>(smem + by1);
        if (s < 39) {
#pragma unroll
            for (int ni = 0; ni < 4; ++ni)
                bn[ni] = wf[(size_t)((s + 1) * 16 + wnl + ni) * 64 + lane];
        }
#pragma unroll
        for (int ni = 0; ni < 4; ++ni) {
            acc[0][ni] = __builtin_amdgcn_mfma_f32_16x16x32_bf16(a0, bc[ni], acc[0][ni], 0, 0, 0);
            acc[1][ni] = __builtin_amdgcn_mfma_f32_16x16x32_bf16(a1, bc[ni], acc[1][ni], 0, 0, 0);
        }
#pragma unroll
        for (int ni = 0; ni < 4; ++ni) bc[ni] = bn[ni];
    }

    // ---- fragment-local LN + ReLU + dot epilogue (no m-tile round-trip) ----
    // D layout (m89): col = lane&15, row = 4*(lane>>4)+reg; global row = wm*32+mi*16+...
    float* ps   = reinterpret_cast<float*>(smem + XS_BYTES);  // [64][4] row-sums
    float* pq   = ps + 256;                                   // [64][4] row-sumsq
    float* pdot = pq + 256;                                   // [64][4] dot partials
    float* mus  = pdot + 256;                                 // [64]
    float* rss  = mus + 64;                                   // [64]

    float cbv[4];
#pragma unroll
    for (int ni = 0; ni < 4; ++ni) cbv[ni] = cb[wn * 64 + ni * 16 + (lane & 15)];

#pragma unroll
    for (int mi = 0; mi < 2; ++mi)
#pragma unroll
        for (int r = 0; r < 4; ++r) {
            float s = 0.f, q = 0.f;
#pragma unroll
            for (int ni = 0; ni < 4; ++ni) {
                float v = acc[mi][ni][r] + cbv[ni];
                s += v; q += v * v;
            }
#pragma unroll
            for (int m = 1; m < 16; m <<= 1) {
                s += __shfl_xor(s, m);
                q += __shfl_xor(q, m);
            }
            if ((lane & 15) == 0) {
                int row = wm * 32 + mi * 16 + (lane >> 4) * 4 + r;
                ps[row * 4 + wn] = s;
                pq[row * 4 + wn] = q;
            }
        }
    __syncthreads();
    if (tid < 64) {
        float S = ps[tid * 4] + ps[tid * 4 + 1] + ps[tid * 4 + 2] + ps[tid * 4 + 3];
        float Q = pq[tid * 4] + pq[tid * 4 + 1] + pq[tid * 4 + 2] + pq[tid * 4 + 3];
        float mu = S * (1.f / 256.f);
        float var = Q * (1.f / 256.f) - mu * mu;
        mus[tid] = mu;
        rss[tid] = rsqrtf(var + 1e-5f);
    }
    __syncthreads();

    float gv[4], bv[4], lv[4];
#pragma unroll
    for (int ni = 0; ni < 4; ++ni) {
        int col = wn * 64 + ni * 16 + (lane & 15);
        gv[ni] = g[col]; bv[ni] = beta[col]; lv[ni] = lw[col];
    }
#pragma unroll
    for (int mi = 0; mi < 2; ++mi)
#pragma unroll
        for (int r = 0; r < 4; ++r) {
            int row = wm * 32 + mi * 16 + (lane >> 4) * 4 + r;
            float mu = mus[row], rs = rss[row];
            float dt = 0.f;
#pragma unroll
            for (int ni = 0; ni < 4; ++ni) {
                float v = acc[mi][ni][r] + cbv[ni];
                float y = fmaxf((v - mu) * rs * gv[ni] + bv[ni], 0.f);
                dt += y * lv[ni];
            }
#pragma unroll
            for (int m = 1; m < 16; m <<= 1) dt += __shfl_xor(dt, m);
            if ((lane & 15) == 0) pdot[row * 4 + wn] = dt;
        }
    __syncthreads();
    if (tid < 64) {
        float dot = pdot[tid * 4] + pdot[tid * 4 + 1] + pdot[tid * 4 + 2] + pdot[tid * 4 + 3]
                  + lb[0];
        int t = t0 + tid;
        m_out[b * T_TOK + t] = (t < tn[b]) ? dot : 0.f;
    }
}

// ---- mels_num_predicted = float(int(sum(exp(m[valid])))) ----
__global__ __launch_bounds__(256) void mels_kernel(const float* __restrict__ m,
                                                   const int* __restrict__ tn,
                                                   float* __restrict__ out) {
    int b = blockIdx.x;
    int tid = threadIdx.x;
    int n = tn[b];
    float s = 0.f;
    for (int t = tid; t < T_TOK; t += 256)
        if (t < n) s += expf(m[b * T_TOK + t]);
    __shared__ float red[4];
    int lane = tid & 63, wid = tid >> 6;
#pragma unroll
    for (int off = 32; off; off >>= 1) s += __shfl_down(s, off);
    if (lane == 0) red[wid] = s;
    __syncthreads();
    if (tid == 0) {
        float tot = red[0] + red[1] + red[2] + red[3];
        out[b] = (float)((int)tot);
    }
}

extern "C" void kernel_launch(void* const* d_in, const int* in_sizes, int n_in,
                              void* d_out, int out_size, void* d_ws, size_t ws_size,
                              hipStream_t stream) {
    const float* x          = (const float*)d_in[0];
    const int*   token_nums = (const int*)d_in[1];
    const float* align      = (const float*)d_in[2];
    const int*   gt         = (const int*)d_in[3];
    // conv1 branch (d_in[4..7]) is dead in the reference
    const float* w2  = (const float*)d_in[8];
    const float* b2  = (const float*)d_in[9];
    const float* g2  = (const float*)d_in[10];
    const float* be2 = (const float*)d_in[11];
    const float* lw  = (const float*)d_in[12];
    const float* lb  = (const float*)d_in[13];

    float* out   = (float*)d_out;
    float* xnew  = out;                                        // [B, T_MEL, H]
    float* m_out = out + (size_t)B_SZ * T_MEL * H_DIM;         // [B, T_TOK]
    float* mels  = m_out + (size_t)B_SZ * T_TOK;               // [B]

    short* wr  = (short*)d_ws;                                 // 40*16*64*8 bf16 = 640KB
    float* cum = (float*)((char*)d_ws + (size_t)40 * 16 * 64 * 8 * 2);

    prep_kernel<<<192, 256, 0, stream>>>(w2, wr, align, gt, cum);
    fused_kernel<<<CONV_BLOCKS + EXPAND_BLOCKS, 512, 0, stream>>>(
        x, wr, b2, g2, be2, lw, lb, token_nums, cum, m_out, xnew);
    mels_kernel<<<B_SZ, 256, 0, stream>>>(m_out, token_nums, mels);
}